// Round 1
// baseline (145.245 us; speedup 1.0000x reference)
//
#include <hip/hip_runtime.h>
#include <math.h>

// SPLFullLoss: x, ref f32[B=32, N=4096, D=512] -> scalar
//   a = -(1/(N*B)) * sum_rows  Sxr / (max(sqrt(Sxx),eps)*max(sqrt(Srr),eps))   (rows along D)
//   b = -(1/(D*B)) * sum_cols  Sxr / (max(sqrt(Sxx),eps)*max(sqrt(Srr),eps))   (cols along N)
// Single streaming pass computes all six moment sets.

#define BB 32
#define NN 4096
#define DD 512

static constexpr float EPS = 1e-12f;
static constexpr int BPB   = 64;        // blocks per batch
static constexpr int RPB   = NN / BPB;  // 64 rows per block
static constexpr int NWAVE = 4;         // 256 threads
static constexpr int RPW   = RPB / NWAVE; // 16 rows per wave

// ws layout (floats): cxx[B*D] | crr[B*D] | cxr[B*D] | row_tot[1]
static constexpr size_t WS_CXX = 0;
static constexpr size_t WS_CRR = (size_t)BB * DD;
static constexpr size_t WS_CXR = (size_t)2 * BB * DD;
static constexpr size_t WS_ROW = (size_t)3 * BB * DD;
static constexpr size_t WS_FLOATS = WS_ROW + 1;

__global__ __launch_bounds__(256) void spl_pass1(
    const float* __restrict__ x, const float* __restrict__ r, float* __restrict__ ws) {
  __shared__ float lds[NWAVE][3][DD];   // 24 KiB
  __shared__ float ldsrow[NWAVE];

  const int tid  = threadIdx.x;
  const int wave = tid >> 6;
  const int lane = tid & 63;
  const int blk  = blockIdx.x;
  const int b    = blk / BPB;
  const int bib  = blk % BPB;
  const int n0   = bib * RPB + wave * RPW;

  float cxx[8], crr[8], cxr[8];
#pragma unroll
  for (int j = 0; j < 8; ++j) { cxx[j] = 0.f; crr[j] = 0.f; cxr[j] = 0.f; }
  float rowacc = 0.f;

  const size_t base_b = (size_t)b * NN * DD;

  for (int rr = 0; rr < RPW; ++rr) {
    const int n = n0 + rr;
    const float4* xp = (const float4*)(x + base_b + (size_t)n * DD);
    const float4* rp = (const float4*)(r + base_b + (size_t)n * DD);
    float4 x0 = xp[lane];
    float4 x1 = xp[lane + 64];
    float4 r0 = rp[lane];
    float4 r1 = rp[lane + 64];

    float sxx = 0.f, srr = 0.f, sxr = 0.f;
    {
      const float xs[4] = {x0.x, x0.y, x0.z, x0.w};
      const float rs[4] = {r0.x, r0.y, r0.z, r0.w};
#pragma unroll
      for (int j = 0; j < 4; ++j) {
        const float pxx = xs[j] * xs[j];
        const float prr = rs[j] * rs[j];
        const float pxr = xs[j] * rs[j];
        sxx += pxx; srr += prr; sxr += pxr;
        cxx[j] += pxx; crr[j] += prr; cxr[j] += pxr;
      }
    }
    {
      const float xs[4] = {x1.x, x1.y, x1.z, x1.w};
      const float rs[4] = {r1.x, r1.y, r1.z, r1.w};
#pragma unroll
      for (int j = 0; j < 4; ++j) {
        const float pxx = xs[j] * xs[j];
        const float prr = rs[j] * rs[j];
        const float pxr = xs[j] * rs[j];
        sxx += pxx; srr += prr; sxr += pxr;
        cxx[4 + j] += pxx; crr[4 + j] += prr; cxr[4 + j] += pxr;
      }
    }
    // wave64 butterfly: every lane ends with the full row sums
#pragma unroll
    for (int off = 1; off < 64; off <<= 1) {
      sxx += __shfl_xor(sxx, off, 64);
      srr += __shfl_xor(srr, off, 64);
      sxr += __shfl_xor(sxr, off, 64);
    }
    const float nx = fmaxf(sqrtf(sxx), EPS);
    const float nr = fmaxf(sqrtf(srr), EPS);
    rowacc += sxr / (nx * nr);
  }

  // stash per-wave column partials
#pragma unroll
  for (int k = 0; k < 2; ++k) {
#pragma unroll
    for (int j = 0; j < 4; ++j) {
      const int d = k * 256 + lane * 4 + j;
      lds[wave][0][d] = cxx[k * 4 + j];
      lds[wave][1][d] = crr[k * 4 + j];
      lds[wave][2][d] = cxr[k * 4 + j];
    }
  }
  if (lane == 0) ldsrow[wave] = rowacc;
  __syncthreads();

  float* cxx_g = ws + WS_CXX;
  float* crr_g = ws + WS_CRR;
  float* cxr_g = ws + WS_CXR;
  for (int d = tid; d < DD; d += 256) {
    float s0 = 0.f, s1 = 0.f, s2 = 0.f;
#pragma unroll
    for (int w = 0; w < NWAVE; ++w) {
      s0 += lds[w][0][d];
      s1 += lds[w][1][d];
      s2 += lds[w][2][d];
    }
    atomicAdd(&cxx_g[b * DD + d], s0);
    atomicAdd(&crr_g[b * DD + d], s1);
    atomicAdd(&cxr_g[b * DD + d], s2);
  }
  if (tid == 0) {
    atomicAdd(ws + WS_ROW, ldsrow[0] + ldsrow[1] + ldsrow[2] + ldsrow[3]);
  }
}

__global__ __launch_bounds__(256) void spl_pass2(const float* __restrict__ ws,
                                                 float* __restrict__ out) {
  const int tid = threadIdx.x;
  const float* cxx_g = ws + WS_CXX;
  const float* crr_g = ws + WS_CRR;
  const float* cxr_g = ws + WS_CXR;

  float acc = 0.f;
  for (int i = tid; i < BB * DD; i += 256) {
    const float sxx = cxx_g[i];
    const float srr = crr_g[i];
    const float sxr = cxr_g[i];
    const float nx = fmaxf(sqrtf(sxx), EPS);
    const float nr = fmaxf(sqrtf(srr), EPS);
    acc += sxr / (nx * nr);
  }
#pragma unroll
  for (int off = 1; off < 64; off <<= 1) acc += __shfl_xor(acc, off, 64);

  __shared__ float wsum[4];
  if ((tid & 63) == 0) wsum[tid >> 6] = acc;
  __syncthreads();
  if (tid == 0) {
    const float colsum = wsum[0] + wsum[1] + wsum[2] + wsum[3];
    const float rowsum = ws[WS_ROW];
    const float a = -rowsum / ((float)NN * (float)BB);
    const float b = -colsum / ((float)DD * (float)BB);
    out[0] = a + b;
  }
}

extern "C" void kernel_launch(void* const* d_in, const int* in_sizes, int n_in,
                              void* d_out, int out_size, void* d_ws, size_t ws_size,
                              hipStream_t stream) {
  const float* x = (const float*)d_in[0];
  const float* r = (const float*)d_in[1];
  float* out = (float*)d_out;
  float* ws = (float*)d_ws;

  (void)in_sizes; (void)n_in; (void)out_size; (void)ws_size;

  hipMemsetAsync(ws, 0, WS_FLOATS * sizeof(float), stream);
  spl_pass1<<<BB * BPB, 256, 0, stream>>>(x, r, ws);
  spl_pass2<<<1, 256, 0, stream>>>(ws, out);
}